// Round 1
// baseline (1932.486 us; speedup 1.0000x reference)
//
#include <hip/hip_runtime.h>
#include <cstdint>
#include <cstddef>

// ---------------------------------------------------------------------------
// SpatialGRU: 2D GRU recurrence over a 32x32 grid, B=64, U=64, C=64.
//   cell(i,j) <- f(h(i-1,j) [top], h(i,j-1) [left], h(i-1,j-1) [diag], x(i,j))
// Strategy: persistent kernel, 32 row-WGs x 4 batch-tiles (16 batches each).
// Each WG sweeps its row j=0..31. Row i consumes row i-1's h via global
// memory + per-cell flags (device-scope atomics -> cross-XCD safe).
// h_left / h_diag are rotated inside LDS (diag(j) = top(j-1)).
// ---------------------------------------------------------------------------

#define LDIM   32
#define BATCH  64
#define UNITS  64
#define CHAN   64
#define NBT    4          // batch tiles
#define BT     16         // batches per tile
#define TPB    512        // threads per block (8 waves)
#define KQ     256        // q = [h_top(64) h_left(64) h_diag(64) s_ij(64)]
#define NG1    448        // gemm1 output cols: r(192) ++ z(256)

// workspace layout:
//   flags : int[32*32*NBT]                  at byte offset 0        (16 KB)
//   states: float[32][32][BATCH][UNITS]     at byte offset 16384    (16.78 MB)
#define FLAGS_BYTES (LDIM * LDIM * NBT * 4)

__global__ __launch_bounds__(TPB) void zero_flags_kernel(int* __restrict__ f) {
    int i = blockIdx.x * TPB + threadIdx.x;
    if (i < LDIM * LDIM * NBT) f[i] = 0;
}

__global__ __launch_bounds__(TPB) void spatial_gru_kernel(
    const float* __restrict__ x,     // (B, C, 32, 32)
    const float* __restrict__ W,     // (256, 448) row-major
    const float* __restrict__ Urec,  // (192, 64)
    const float* __restrict__ bias,  // (512,)
    const float* __restrict__ Wij,   // (64, 64)
    float* __restrict__ out,         // (B, U)
    int* __restrict__ flags,
    float* __restrict__ states)      // (32, 32, B, U)
{
    const int bid = blockIdx.x;
    const int row = bid >> 2;     // 0..31
    const int bt  = bid & 3;      // 0..3
    const int b0  = bt * BT;
    const int t   = (int)threadIdx.x;
    const int u   = t & 63;       // lane-ish: output unit / col id
    const int g   = t >> 6;       // wave id 0..7 (uniform per wave)
    const int bq  = g & 3;        // GEMM1 batch-quad base
    const int mh  = g >> 2;       // GEMM1 col-half: 0 -> cols [0,256), 1 -> [256,448)

    // LDS (+1 padding on the 16-wide dims to break 32-bank aliasing)
    __shared__ float qs [KQ ][BT + 1];  // q^T: [k][b]; rows 0:64 hT, 64:128 hL, 128:192 hD, 192:256 s_ij
    __shared__ float rhs_[192][BT + 1]; // (r * h_sel)^T for GEMM2
    __shared__ float Gs [BT ][NG1 + 1]; // GEMM1 result: [b][n]

    // hoisted biases (G init = bias[n]; b_ij = bias[448+u])
    float bb[4];
    if (mh == 0) {
        bb[0] = bias[u];       bb[1] = bias[u + 64];
        bb[2] = bias[u + 128]; bb[3] = bias[u + 192];
    } else {
        bb[0] = bias[u + 256]; bb[1] = bias[u + 320];
        bb[2] = bias[u + 384]; bb[3] = 0.f;
    }
    const float bij = bias[448 + u];

    // zero hT/hL/hD (boundary condition: states0 == 0)
    for (int idx = t; idx < 192 * BT; idx += TPB) {
        int b = idx & 15, k = idx >> 4;
        qs[k][b] = 0.f;
    }
    __syncthreads();

    for (int j = 0; j < LDIM; ++j) {
        // ---- [A] load s_ij -> qs rows 192:256 (plain loads; input is immutable)
        for (int idx = t; idx < CHAN * BT; idx += TPB) {   // 2 iters
            int c = idx & 63, b = idx >> 6;
            qs[192 + c][b] =
                x[(size_t)(b0 + b) * (CHAN * LDIM * LDIM) + (size_t)c * (LDIM * LDIM)
                  + row * LDIM + j];
        }
        // ---- [B] wait for row-1 cell j, then load h_top -> qs rows 0:64
        if (row > 0) {
            const int* fl = flags + ((row - 1) * LDIM + j) * NBT + bt;
            while (__hip_atomic_load(fl, __ATOMIC_RELAXED, __HIP_MEMORY_SCOPE_AGENT) == 0) {
                __builtin_amdgcn_s_sleep(2);
            }
            asm volatile("" ::: "memory");  // keep data loads after flag observation
            for (int idx = t; idx < BT * UNITS; idx += TPB) {  // 2 iters
                int uu = idx & 63, b = idx >> 6;
                qs[uu][b] = __hip_atomic_load(
                    states + (((size_t)(row - 1) * LDIM + j) * BATCH + b0 + b) * UNITS + uu,
                    __ATOMIC_RELAXED, __HIP_MEMORY_SCOPE_AGENT);
            }
        }
        __syncthreads();

        // ---- [C] GEMM1: G[b][n] = bias[n] + sum_k q[k][b] * W[k][n]
        // thread covers b in {bq, bq+4, bq+8, bq+12}; cols u + 64*m (m-half by mh)
        float acc[4][4];
#pragma unroll
        for (int i = 0; i < 4; ++i) {
            acc[i][0] = bb[0]; acc[i][1] = bb[1]; acc[i][2] = bb[2]; acc[i][3] = bb[3];
        }
        if (mh == 0) {
#pragma unroll 2
            for (int k = 0; k < KQ; ++k) {
                const float* wk = W + (size_t)k * NG1 + u;
                float w0 = wk[0], w1 = wk[64], w2 = wk[128], w3 = wk[192];
                float q0 = qs[k][bq], q1 = qs[k][bq + 4], q2 = qs[k][bq + 8], q3 = qs[k][bq + 12];
                acc[0][0] += q0 * w0; acc[0][1] += q0 * w1; acc[0][2] += q0 * w2; acc[0][3] += q0 * w3;
                acc[1][0] += q1 * w0; acc[1][1] += q1 * w1; acc[1][2] += q1 * w2; acc[1][3] += q1 * w3;
                acc[2][0] += q2 * w0; acc[2][1] += q2 * w1; acc[2][2] += q2 * w2; acc[2][3] += q2 * w3;
                acc[3][0] += q3 * w0; acc[3][1] += q3 * w1; acc[3][2] += q3 * w2; acc[3][3] += q3 * w3;
            }
#pragma unroll
            for (int i = 0; i < 4; ++i) {
                int b = bq + 4 * i;
                Gs[b][u]       = acc[i][0];
                Gs[b][u + 64]  = acc[i][1];
                Gs[b][u + 128] = acc[i][2];
                Gs[b][u + 192] = acc[i][3];
            }
        } else {
#pragma unroll 2
            for (int k = 0; k < KQ; ++k) {
                const float* wk = W + (size_t)k * NG1 + 256 + u;
                float w0 = wk[0], w1 = wk[64], w2 = wk[128];
                float q0 = qs[k][bq], q1 = qs[k][bq + 4], q2 = qs[k][bq + 8], q3 = qs[k][bq + 12];
                acc[0][0] += q0 * w0; acc[0][1] += q0 * w1; acc[0][2] += q0 * w2;
                acc[1][0] += q1 * w0; acc[1][1] += q1 * w1; acc[1][2] += q1 * w2;
                acc[2][0] += q2 * w0; acc[2][1] += q2 * w1; acc[2][2] += q2 * w2;
                acc[3][0] += q3 * w0; acc[3][1] += q3 * w1; acc[3][2] += q3 * w2;
            }
#pragma unroll
            for (int i = 0; i < 4; ++i) {
                int b = bq + 4 * i;
                Gs[b][u + 256] = acc[i][0];
                Gs[b][u + 320] = acc[i][1];
                Gs[b][u + 384] = acc[i][2];
            }
        }
        __syncthreads();

        // ---- [D] r = sigmoid(G[:, :192]); rh[k][b] = r * {hL,hT,hD}[k]
        // NOTE reference: h_hat uses r * concat([h_left, h_top, h_diag])
        for (int idx = t; idx < 192 * BT; idx += TPB) {   // 6 iters
            int b = idx & 15, k = idx >> 4;
            float gv = Gs[b][k];
            float r  = 1.f / (1.f + __expf(-gv));
            float hv = (k < 64) ? qs[64 + k][b]               // h_left
                     : (k < 128) ? qs[k - 64][b]              // h_top
                                 : qs[k][b];                  // h_diag
            rhs_[k][b] = r * hv;
        }
        __syncthreads();

        // ---- [E] GEMM2: hh = tanh(b_ij + rh @ U_rec + s_ij @ W_ij)
        // thread covers b in {g, g+8}, unit u
        float h0 = bij, h1 = bij;
#pragma unroll 4
        for (int k = 0; k < 192; ++k) {
            float w = Urec[k * 64 + u];
            h0 += rhs_[k][g] * w;
            h1 += rhs_[k][g + 8] * w;
        }
#pragma unroll 4
        for (int c = 0; c < 64; ++c) {
            float w = Wij[c * 64 + u];
            h0 += qs[192 + c][g] * w;
            h1 += qs[192 + c][g + 8] * w;
        }
        float hh[2] = { tanhf(h0), tanhf(h1) };

        // ---- [F] softmax gates over {zi,zl,zt,zd}; h = zl*hL+zt*hT+zd*hD+zi*hh
        float hnew[2];
#pragma unroll
        for (int i = 0; i < 2; ++i) {
            int b = g + 8 * i;
            float zi = Gs[b][192 + u], zl = Gs[b][256 + u];
            float zt = Gs[b][320 + u], zd = Gs[b][384 + u];
            float mx = fmaxf(fmaxf(zi, zl), fmaxf(zt, zd));
            float ei = __expf(zi - mx), el = __expf(zl - mx);
            float et = __expf(zt - mx), ed = __expf(zd - mx);
            float inv = 1.f / (ei + el + et + ed);
            float hL = qs[64 + u][b], hT = qs[u][b], hD = qs[128 + u][b];
            float hv = (el * hL + et * hT + ed * hD + ei * hh[i]) * inv;
            hnew[i] = hv;
            // device-scope (agent) store: per-access cache bypass -> visible cross-XCD
            __hip_atomic_store(
                states + (((size_t)row * LDIM + j) * BATCH + b0 + b) * UNITS + u,
                hv, __ATOMIC_RELAXED, __HIP_MEMORY_SCOPE_AGENT);
            if (row == LDIM - 1 && j == LDIM - 1)
                out[(size_t)(b0 + b) * UNITS + u] = hv;
        }
        __syncthreads();   // all qs reads (rows 0:192) done; all state stores issued

        // ---- [G] rotate LDS state: hD <- hT ; hL <- hnew (rows 64:192 written,
        // rows 0:64 read -> disjoint, no intra-phase race)
#pragma unroll
        for (int i = 0; i < 2; ++i) {
            int b = g + 8 * i;
            qs[128 + u][b] = qs[u][b];
            qs[64 + u][b]  = hnew[i];
        }
        // make THIS thread's state stores globally complete before the flag
        asm volatile("s_waitcnt vmcnt(0)" ::: "memory");
        __syncthreads();   // now every thread's stores are complete
        if (t == 0) {
            __hip_atomic_store(flags + (row * LDIM + j) * NBT + bt, 1,
                               __ATOMIC_RELAXED, __HIP_MEMORY_SCOPE_AGENT);
        }
    }
}

extern "C" void kernel_launch(void* const* d_in, const int* in_sizes, int n_in,
                              void* d_out, int out_size, void* d_ws, size_t ws_size,
                              hipStream_t stream) {
    const float* x    = (const float*)d_in[0];  // inputs (64,64,32,32)
    const float* W    = (const float*)d_in[1];  // (256,448)
    const float* Urec = (const float*)d_in[2];  // (192,64)
    const float* bias = (const float*)d_in[3];  // (512,)
    const float* Wij  = (const float*)d_in[4];  // (64,64)
    float* out = (float*)d_out;                 // (64,64)

    int*   flags  = (int*)d_ws;
    float* states = (float*)((char*)d_ws + 16384);

    // ws is re-poisoned before every launch: flags must be zeroed each call.
    int nflags = LDIM * LDIM * NBT;
    zero_flags_kernel<<<(nflags + TPB - 1) / TPB, TPB, 0, stream>>>(flags);

    spatial_gru_kernel<<<LDIM * NBT, TPB, 0, stream>>>(
        x, W, Urec, bias, Wij, out, flags, states);
}

// Round 2
// 349.035 us; speedup vs baseline: 5.5367x; 5.5367x over previous
//
#include <hip/hip_runtime.h>
#include <cstdint>
#include <cstddef>

// ---------------------------------------------------------------------------
// SpatialGRU 32x32 grid, B=64, U=64, C=64. Persistent: 32 rows x 4 batch-tiles
// of 16. Cross-row h passed via global states + flags (agent-scope atomics).
// R2: all weights resident in VGPRs as f16; GEMM1 (16x448x256) on waves 0-6
// via v_mfma_f32_16x16x32_f16 (64 cols/wave held in 128 VGPRs); GEMM2
// (16x64x256, [U_rec;W_ij]) on wave 7 with the SAME uniform register array.
// ---------------------------------------------------------------------------

#define LDIM   32
#define BATCH  64
#define UNITS  64
#define CHAN   64
#define NBT    4
#define BT     16
#define TPB    512

typedef _Float16 f16;
typedef _Float16 f16x8 __attribute__((ext_vector_type(8)));
typedef float    f32x4 __attribute__((ext_vector_type(4)));

__global__ __launch_bounds__(TPB) void zero_flags_kernel(int* __restrict__ f) {
    int i = blockIdx.x * TPB + threadIdx.x;
    if (i < LDIM * LDIM * NBT) f[i] = 0;
}

__global__ __launch_bounds__(TPB, 2) void spatial_gru_kernel(
    const float* __restrict__ x,     // (B, C, 32, 32)
    const float* __restrict__ W,     // (256, 448)
    const float* __restrict__ Urec,  // (192, 64)
    const float* __restrict__ bias,  // (512,)
    const float* __restrict__ Wij,   // (64, 64)
    float* __restrict__ out,         // (B, U)
    int* __restrict__ flags,
    float* __restrict__ states)      // (32, 32, B, U)
{
    const int bid = blockIdx.x;
    const int row = bid >> 2;
    const int bt  = bid & 3;
    const int b0  = bt * BT;
    const int t   = (int)threadIdx.x;
    const int u   = t & 63;
    const int g   = t >> 6;          // wave id 0..7 (uniform per wave)
    const int l15 = t & 15;          // MFMA: n-col within tile / m-row
    const int lq  = (t & 63) >> 4;   // MFMA: k-quad (0..3)

    // ---- LDS ----
    // qf : A-layout q (f16)   [m=b][k]  k: 0:64 hT | 64:128 hL | 128:192 hD | 192:256 s
    // rf : A-layout GEMM2 in  [m=b][k]  k: 0:192 r*h | 192:256 s
    // qs32: fp32 h state      [k][b]    k: 0:64 hT | 64:128 hL | 128:192 hD
    // Gs : GEMM1 out (fp32)   [b][n]    n: 0:192 r-logits | 192:448 z-logits
    __shared__ __attribute__((aligned(16))) f16 qf[BT][264];
    __shared__ __attribute__((aligned(16))) f16 rf[BT][264];
    __shared__ float qs32[192][BT + 1];
    __shared__ float Gs[BT][452];
    __shared__ float hh[BT][64];

    // ---- preload weights into registers (f16), UNIFORM array across waves ----
    f16x8 wreg[4][8];   // [n-tile][k-step]: lane l holds B[k=32s+8*lq+jj][n=base+16T+l15]
    float bias1[4];
    if (g < 7) {
        const int nb = g * 64 + l15;
#pragma unroll
        for (int T = 0; T < 4; ++T) {
            bias1[T] = bias[nb + 16 * T];
#pragma unroll
            for (int s = 0; s < 8; ++s) {
                f16x8 v;
#pragma unroll
                for (int jj = 0; jj < 8; ++jj) {
                    int kk = s * 32 + lq * 8 + jj;
                    v[jj] = (f16)W[(size_t)kk * 448 + nb + 16 * T];
                }
                wreg[T][s] = v;
            }
        }
    } else {
#pragma unroll
        for (int T = 0; T < 4; ++T) {
            const int nn = T * 16 + l15;
            bias1[T] = bias[448 + nn];
#pragma unroll
            for (int s = 0; s < 8; ++s) {
                f16x8 v;
#pragma unroll
                for (int jj = 0; jj < 8; ++jj) {
                    int kk = s * 32 + lq * 8 + jj;
                    float wv = (kk < 192) ? Urec[kk * 64 + nn] : Wij[(kk - 192) * 64 + nn];
                    v[jj] = (f16)wv;
                }
                wreg[T][s] = v;
            }
        }
    }

    // ---- zero initial state (states0 == 0) ----
    for (int idx = t; idx < 192 * BT; idx += TPB) {
        int b = idx & 15, k = idx >> 4;
        qs32[k][b] = 0.f;
        qf[b][k] = (f16)0.f;
    }
    __syncthreads();

    const int bA = t >> 6;           // 0..7; thread covers batches bA and bA+8

    for (int j = 0; j < LDIM; ++j) {
        // ---- [A] prefetch x into regs (overlaps the flag spin) ----
        const size_t xoff = (size_t)u * 1024 + (size_t)row * 32 + j;
        float x0 = x[(size_t)(b0 + bA) * 65536 + xoff];
        float x1 = x[(size_t)(b0 + bA + 8) * 65536 + xoff];

        // ---- [B] wait for (row-1, j), load h_top ----
        float ht0 = 0.f, ht1 = 0.f;
        if (row > 0) {
            const int* fl = flags + ((row - 1) * LDIM + j) * NBT + bt;
            while (__hip_atomic_load(fl, __ATOMIC_RELAXED, __HIP_MEMORY_SCOPE_AGENT) == 0) {
                __builtin_amdgcn_s_sleep(2);
            }
            asm volatile("" ::: "memory");
            const float* sp = states + (((size_t)(row - 1) * LDIM + j) * BATCH + b0) * UNITS;
            ht0 = __hip_atomic_load(sp + (size_t)bA * 64 + u,
                                    __ATOMIC_RELAXED, __HIP_MEMORY_SCOPE_AGENT);
            ht1 = __hip_atomic_load(sp + (size_t)(bA + 8) * 64 + u,
                                    __ATOMIC_RELAXED, __HIP_MEMORY_SCOPE_AGENT);
        }
        // stage into LDS
        qf[bA][192 + u]     = (f16)x0;  rf[bA][192 + u]     = (f16)x0;
        qf[bA + 8][192 + u] = (f16)x1;  rf[bA + 8][192 + u] = (f16)x1;
        qs32[u][bA]     = ht0;  qf[bA][u]     = (f16)ht0;
        qs32[u][bA + 8] = ht1;  qf[bA + 8][u] = (f16)ht1;
        __syncthreads();   // s1

        // ---- [C] GEMM1: G = bias + q @ W   (waves 0..6, 64 cols each) ----
        if (g < 7) {
            f32x4 acc[4];
#pragma unroll
            for (int T = 0; T < 4; ++T)
                acc[T] = (f32x4){bias1[T], bias1[T], bias1[T], bias1[T]};
#pragma unroll
            for (int s = 0; s < 8; ++s) {
                f16x8 a = *(const f16x8*)&qf[l15][s * 32 + lq * 8];
#pragma unroll
                for (int T = 0; T < 4; ++T)
                    acc[T] = __builtin_amdgcn_mfma_f32_16x16x32_f16(a, wreg[T][s], acc[T], 0, 0, 0);
            }
#pragma unroll
            for (int T = 0; T < 4; ++T)
#pragma unroll
                for (int r = 0; r < 4; ++r)
                    Gs[lq * 4 + r][g * 64 + T * 16 + l15] = acc[T][r];
        }
        __syncthreads();   // s2

        // ---- [D] r = sigmoid(G[:, :192]); rf = f16(r * {hL,hT,hD}) ----
        for (int idx = t; idx < 192 * BT; idx += TPB) {   // 6 iters
            int b = idx & 15, k = idx >> 4;
            float gv = Gs[b][k];
            float r  = 1.f / (1.f + __expf(-gv));
            float hv = (k < 64) ? qs32[64 + k][b]
                     : (k < 128) ? qs32[k - 64][b]
                                 : qs32[k][b];
            rf[b][k] = (f16)(r * hv);
        }
        __syncthreads();   // s3

        // ---- [E] GEMM2: h_hat = tanh(bij + [r*h, s] @ [Urec; Wij]) (wave 7) ----
        if (g == 7) {
            f32x4 acc[4];
#pragma unroll
            for (int T = 0; T < 4; ++T)
                acc[T] = (f32x4){bias1[T], bias1[T], bias1[T], bias1[T]};
#pragma unroll
            for (int s = 0; s < 8; ++s) {
                f16x8 a = *(const f16x8*)&rf[l15][s * 32 + lq * 8];
#pragma unroll
                for (int T = 0; T < 4; ++T)
                    acc[T] = __builtin_amdgcn_mfma_f32_16x16x32_f16(a, wreg[T][s], acc[T], 0, 0, 0);
            }
#pragma unroll
            for (int T = 0; T < 4; ++T)
#pragma unroll
                for (int r = 0; r < 4; ++r) {
                    float v = acc[T][r];
                    float th = 1.f - 2.f / (1.f + __expf(2.f * v));  // tanh
                    hh[lq * 4 + r][T * 16 + l15] = th;
                }
        }
        __syncthreads();   // s4

        // ---- [F] softmax gates + output + state rotation (fused; per-(u,b) slots) ----
#pragma unroll
        for (int i = 0; i < 2; ++i) {
            int b = bA + 8 * i;
            float zi = Gs[b][192 + u], zl = Gs[b][256 + u];
            float zt = Gs[b][320 + u], zd = Gs[b][384 + u];
            float mx = fmaxf(fmaxf(zi, zl), fmaxf(zt, zd));
            float ei = __expf(zi - mx), el = __expf(zl - mx);
            float et = __expf(zt - mx), ed = __expf(zd - mx);
            float inv = 1.f / (ei + el + et + ed);
            float hL = qs32[64 + u][b], hT = qs32[u][b], hD = qs32[128 + u][b];
            float hv = (el * hL + et * hT + ed * hD + ei * hh[b][u]) * inv;

            __hip_atomic_store(
                states + (((size_t)row * LDIM + j) * BATCH + b0 + b) * UNITS + u,
                hv, __ATOMIC_RELAXED, __HIP_MEMORY_SCOPE_AGENT);
            if (row == LDIM - 1 && j == LDIM - 1)
                out[(size_t)(b0 + b) * UNITS + u] = hv;

            // rotate: hD <- hT, hL <- h_new (this thread owns these slots)
            qs32[128 + u][b] = hT;
            qs32[64 + u][b]  = hv;
            f16 htf = qf[b][u];
            qf[b][128 + u] = htf;
            qf[b][64 + u]  = (f16)hv;
        }
        asm volatile("s_waitcnt vmcnt(0)" ::: "memory");
        __syncthreads();   // s5 — all state stores drained, all rotations done
        if (t == 0) {
            __hip_atomic_store(flags + (row * LDIM + j) * NBT + bt, 1,
                               __ATOMIC_RELAXED, __HIP_MEMORY_SCOPE_AGENT);
        }
    }
}

extern "C" void kernel_launch(void* const* d_in, const int* in_sizes, int n_in,
                              void* d_out, int out_size, void* d_ws, size_t ws_size,
                              hipStream_t stream) {
    const float* x    = (const float*)d_in[0];
    const float* W    = (const float*)d_in[1];
    const float* Urec = (const float*)d_in[2];
    const float* bias = (const float*)d_in[3];
    const float* Wij  = (const float*)d_in[4];
    float* out = (float*)d_out;

    int*   flags  = (int*)d_ws;
    float* states = (float*)((char*)d_ws + 16384);

    int nflags = LDIM * LDIM * NBT;
    zero_flags_kernel<<<(nflags + TPB - 1) / TPB, TPB, 0, stream>>>(flags);

    spatial_gru_kernel<<<LDIM * NBT, TPB, 0, stream>>>(
        x, W, Urec, bias, Wij, out, flags, states);
}